// Round 3
// baseline (302.440 us; speedup 1.0000x reference)
//
#include <hip/hip_runtime.h>
#include <hip/hip_bf16.h>

// GraphConvolution: out = relu( (W@x + b) @ adj^T + x ), B=4096, C=256, N=25.
// R8: single-barrier software pipeline. R7 was barrier-convoy + LDS-pipe bound
// (3 barriers/iter, ~85 ds-ops/wave/iter, all pipes <30%). Changes:
//  - ONE barrier per iteration: phase = { gemm(bi) | epilogue(bi) |
//    gload-issue(bi+2) | strided stores(bi) | agg(bi+1) } with ys double-
//    buffered by bi parity. gemm(i) reads ysA while agg(i+1) writes ysB.
//  - outS dropped: stores go straight from epilogue registers (16 posted
//    dword stores; 100B rows merge in L2). -20 LDS ops/wave/iter.
//  - ys shrunk to 25 rows x 2 buffers (bfr1 row clamped to 24; clamped
//    lanes' output columns are discarded). adjbf aliases ys2 at init.
//    LDS = 51200(xs2) + 26400(ys2) + 1024(bias) = 78624 B -> 2 blocks/CU.
//  - vmcnt discipline: entry vmcnt(16) leaves prev stores in flight and
//    forces x[bi+1] landed; lgkmcnt(0) before gload issue orders the DMA
//    after the same-wave residual reads; lgkmcnt(0)+s_barrier per phase.

#define BATCH 4096
#define C 256
#define N 25
#define NB 8
#define XW 6400          // floats per batch tile (256*25), linear layout
#define YSTR 264         // ys bf16 row stride (528 B, 16B-aligned rows)
#define YROWS 25
#define YBUF (YROWS * YSTR)   // 6600 bf16 = 13200 B per buffer

typedef __bf16 bf16x8 __attribute__((ext_vector_type(8)));
typedef float f32x4 __attribute__((ext_vector_type(4)));

#define GLOAD16(gp, lp)                                                        \
    __builtin_amdgcn_global_load_lds(                                          \
        (const __attribute__((address_space(1))) unsigned int*)(gp),           \
        (__attribute__((address_space(3))) unsigned int*)(lp), 16, 0, 0)

// ---- prep: Wshuf[(T*8+kk)*64+lane] = MFMA A-fragment, o-tile T (o=T*16+l15) ----
__global__ void prep_kernel(const float* __restrict__ W, const float* __restrict__ adj,
                            bf16x8* __restrict__ Wshuf, float* __restrict__ adjS) {
    int i = blockIdx.x * 256 + threadIdx.x;       // 8192 = 128 frags x 64 lanes
    int f = i >> 6, l = i & 63;
    int T = f >> 3, kk = f & 7;
    int quad = l >> 4, l15 = l & 15;
    int o = T * 16 + l15;
    int cb = kk * 32 + quad * 8;
    bf16x8 v;
    #pragma unroll
    for (int j = 0; j < 8; ++j) v[j] = (__bf16)W[o * C + cb + j];
    Wshuf[i] = v;
    if (blockIdx.x == 0 && threadIdx.x < 32) {
        float s = 0.f;
        if (threadIdx.x < N)
            for (int n = 0; n < N; ++n) s += adj[threadIdx.x * N + n];
        adjS[threadIdx.x] = s;
    }
}

__global__ __launch_bounds__(512, 4) void gcn_kernel(
    const float* __restrict__ x, const float* __restrict__ adj,
    const float* __restrict__ bias, const float* __restrict__ adjSg,
    const bf16x8* __restrict__ Wshuf, float* __restrict__ out)
{
    __shared__ __align__(16) float  xs2[2][XW];     // 51200 B, linear x tiles
    __shared__ __align__(16) __bf16 ys2[2][YBUF];   // 26400 B, y double-buffer
    __shared__ float biasS[C];                      //  1024 B  (total 78624 B)
    __bf16* const adjbf = &ys2[0][0];               // alias: init-only, 2560 B

    const int tid = threadIdx.x;                   // 0..511
    const int wv = tid >> 6, lane = tid & 63;      // 8 waves
    const int quad = lane >> 4, l15 = lane & 15;
    const int o0 = wv * 32;                        // wave's o-range == c-range
    const int b0 = blockIdx.x * NB;

    // ---- one-time: adj into aliased LDS, bias, pinned W fragments ----
    for (int e = tid; e < 32 * 32; e += 512) {
        int m = e >> 5, n = e & 31;
        adjbf[m * 40 + n] = (m < N && n < N) ? (__bf16)adj[m * N + n] : (__bf16)0.f;
    }
    if (tid < C) biasS[tid] = bias[tid];

    bf16x8 af[8][2];   // 64 VGPRs, coalesced 1KB loads
    #pragma unroll
    for (int kk = 0; kk < 8; ++kk)
        #pragma unroll
        for (int ot = 0; ot < 2; ++ot)
            af[kk][ot] = Wshuf[(((wv * 2 + ot) * 8 + kk) << 6) + lane];

    const float aS0 = adjSg[l15];
    const float aS1 = adjSg[16 + l15];

    __syncthreads();   // adjbf/biasS ready (full drain, once)

    // ---- start DMA for x0, x1 as early as possible ----
    {
        const float4* xb0 = (const float4*)(x + (size_t)b0 * XW);
        const float4* xb1 = (const float4*)(x + (size_t)(b0 + 1) * XW);
        #pragma unroll
        for (int rr = 0; rr < 4; ++rr)
            if (rr < 3 || lane < 8)
                GLOAD16(xb0 + (wv * 200 + rr * 64 + lane),
                        &xs2[0][(wv * 200 + rr * 64) * 4]);
        #pragma unroll
        for (int rr = 0; rr < 4; ++rr)
            if (rr < 3 || lane < 8)
                GLOAD16(xb1 + (wv * 200 + rr * 64 + lane),
                        &xs2[1][(wv * 200 + rr * 64) * 4]);
    }

    const bf16x8 a0 = *(const bf16x8*)&adjbf[l15 * 40 + quad * 8];
    const bf16x8 a1 = *(const bf16x8*)&adjbf[(16 + l15) * 40 + quad * 8];
    // all waves must finish reading adjbf before agg_0 overwrites ys2[0]
    asm volatile("s_waitcnt lgkmcnt(0)" ::: "memory");
    __builtin_amdgcn_s_barrier();

    // agg: y[m][c] = sum_n adj[m][n] * x[c][n] for the wave's 32 c-rows
    auto AGG = [&](const float* xc, __bf16* ysw) {
        #pragma unroll
        for (int ctl = 0; ctl < 2; ++ctl) {
            const int c = o0 + ctl * 16 + l15;
            const float* xr = xc + c * N;
            bf16x8 xf;
            if (quad < 3) {   // n = quad*8..quad*8+7 all < 25
                #pragma unroll
                for (int j = 0; j < 8; ++j) xf[j] = (__bf16)xr[quad * 8 + j];
            } else {          // n = 24..31: only 24 valid (adj k>=25 is 0)
                xf[0] = (__bf16)xr[24];
                #pragma unroll
                for (int j = 1; j < 8; ++j) xf[j] = (__bf16)0.f;
            }
            f32x4 y0 = __builtin_amdgcn_mfma_f32_16x16x32_bf16(a0, xf, (f32x4)0.f, 0, 0, 0);
            f32x4 y1 = __builtin_amdgcn_mfma_f32_16x16x32_bf16(a1, xf, (f32x4)0.f, 0, 0, 0);
            #pragma unroll
            for (int r2 = 0; r2 < 4; ++r2) {
                ysw[(quad * 4 + r2) * YSTR + c] = (__bf16)y0[r2];
                if (quad * 4 + r2 < 9)   // rows 16..24 only (25 rows total)
                    ysw[(16 + quad * 4 + r2) * YSTR + c] = (__bf16)y1[r2];
            }
        }
    };

    // ---- prologue: agg for batch 0 ----
    asm volatile("s_waitcnt vmcnt(4)" ::: "memory");   // x0 landed, x1 in flight
    AGG(xs2[0], ys2[0]);
    asm volatile("s_waitcnt lgkmcnt(0)" ::: "memory");
    __builtin_amdgcn_s_barrier();

    const int row1 = (l15 < 9) ? (16 + l15) : 24;  // clamped ys row (cols discarded)

    #pragma unroll 1
    for (int bi = 0; bi < NB; ++bi) {
        const int cur = bi & 1;
        const float* xc = xs2[cur];
        const __bf16* ysr = ys2[cur];
        float* outb = out + (size_t)(b0 + bi) * XW;

        // entry wait: x[bi+1] landed (needed by agg at end of this phase);
        // leaves the previous phase's 16 stores in flight.
        if (bi == 0)          asm volatile("s_waitcnt vmcnt(0)" ::: "memory");
        else if (bi < NB - 1) asm volatile("s_waitcnt vmcnt(16)" ::: "memory");

        // ---- main GEMM: out[o][m] += W[o][c]*y[c][m]; af pinned in regs ----
        f32x4 acc[2][2];
        #pragma unroll
        for (int ot = 0; ot < 2; ++ot) { acc[ot][0] = (f32x4)0.f; acc[ot][1] = (f32x4)0.f; }
        #pragma unroll
        for (int kk = 0; kk < 8; ++kk) {
            bf16x8 bfr0 = *(const bf16x8*)&ysr[l15  * YSTR + kk * 32 + quad * 8];
            bf16x8 bfr1 = *(const bf16x8*)&ysr[row1 * YSTR + kk * 32 + quad * 8];
            #pragma unroll
            for (int ot = 0; ot < 2; ++ot) {
                acc[ot][0] = __builtin_amdgcn_mfma_f32_16x16x32_bf16(af[kk][ot], bfr0, acc[ot][0], 0, 0, 0);
                acc[ot][1] = __builtin_amdgcn_mfma_f32_16x16x32_bf16(af[kk][ot], bfr1, acc[ot][1], 0, 0, 0);
            }
        }

        // ---- epilogue in registers: residual from xs (own rows) ----
        float ov0[2][4], ov1[2][4];
        #pragma unroll
        for (int ot = 0; ot < 2; ++ot)
            #pragma unroll
            for (int r2 = 0; r2 < 4; ++r2) {
                const int o = o0 + ot * 16 + quad * 4 + r2;
                const float bia = biasS[o];
                float v0 = acc[ot][0][r2] + bia * aS0 + xc[o * N + l15];
                ov0[ot][r2] = v0 > 0.f ? v0 : 0.f;
                float xr1 = (l15 < 9) ? xc[o * N + 16 + l15] : 0.f;
                float v1 = acc[ot][1][r2] + bia * aS1 + xr1;
                ov1[ot][r2] = v1 > 0.f ? v1 : 0.f;
            }

        // residual reads complete before the DMA below may overwrite xs2[cur]
        asm volatile("s_waitcnt lgkmcnt(0)" ::: "memory");

        // ---- issue gloads for x[bi+2] into xs2[cur] (wave-private rows) ----
        if (bi + 2 < NB) {
            const float4* xb = (const float4*)(x + (size_t)(b0 + bi + 2) * XW);
            #pragma unroll
            for (int rr = 0; rr < 4; ++rr)
                if (rr < 3 || lane < 8)
                    GLOAD16(xb + (wv * 200 + rr * 64 + lane),
                            &xs2[cur][(wv * 200 + rr * 64) * 4]);
        }

        // ---- strided stores straight from registers (posted; L2 merges) ----
        #pragma unroll
        for (int ot = 0; ot < 2; ++ot)
            #pragma unroll
            for (int r2 = 0; r2 < 4; ++r2) {
                const int o = o0 + ot * 16 + quad * 4 + r2;
                outb[o * N + l15] = ov0[ot][r2];
                if (l15 < 9) outb[o * N + 16 + l15] = ov1[ot][r2];
            }

        // ---- agg for bi+1 into the other ys buffer ----
        if (bi + 1 < NB)
            AGG(xs2[cur ^ 1], ys2[cur ^ 1]);

        // single phase barrier: ys[bi+1] visible; gemm reads of ys[bi] done.
        asm volatile("s_waitcnt lgkmcnt(0)" ::: "memory");
        __builtin_amdgcn_s_barrier();
    }
}

extern "C" void kernel_launch(void* const* d_in, const int* in_sizes, int n_in,
                              void* d_out, int out_size, void* d_ws, size_t ws_size,
                              hipStream_t stream) {
    (void)in_sizes; (void)n_in; (void)out_size; (void)ws_size;
    const float* x    = (const float*)d_in[0];   // [4096, 256, 25]
    const float* adj  = (const float*)d_in[1];   // [25, 25]
    const float* W    = (const float*)d_in[2];   // [256, 256]
    const float* bias = (const float*)d_in[3];   // [256]
    float* out = (float*)d_out;

    unsigned char* ws = (unsigned char*)d_ws;
    bf16x8* Wshuf = (bf16x8*)ws;                 // 131072 B
    float*  adjS  = (float*)(ws + 131072);       // 128 B

    prep_kernel<<<32, 256, 0, stream>>>(W, adj, Wshuf, adjS);
    gcn_kernel<<<BATCH / NB, 512, 0, stream>>>(x, adj, bias, adjS, Wshuf, out);
}